// Round 12
// baseline (1456.708 us; speedup 1.0000x reference)
//
#include <hip/hip_runtime.h>
#include <hip/hip_bf16.h>
#include <stdint.h>

#define TTOK 2048
#define DDIM 2048
#define IDIM 5632
#define NEXP 8

typedef __attribute__((ext_vector_type(8))) short bf16x8;
typedef __attribute__((ext_vector_type(4))) float f32x4;
typedef __attribute__((ext_vector_type(8))) unsigned short u16x8;
typedef __attribute__((ext_vector_type(4))) unsigned short u16x4;

__device__ __forceinline__ unsigned short f2bf(float f) {
  union { float f; uint32_t u; } v; v.f = f;
  uint32_t u = v.u + 0x7fffu + ((v.u >> 16) & 1u);
  return (unsigned short)(u >> 16);
}

__device__ __forceinline__ uint32_t fbits(float f) {
  union { float f; uint32_t u; } v; v.f = f; return v.u;
}

// truncating packed f32x2 -> bf16x2 via v_perm_b32
__device__ __forceinline__ u16x8 cvt8t(float4 a, float4 b) {
  union { u16x8 v; uint32_t w[4]; } r;
  r.w[0] = __builtin_amdgcn_perm(fbits(a.y), fbits(a.x), 0x07060302);
  r.w[1] = __builtin_amdgcn_perm(fbits(a.w), fbits(a.z), 0x07060302);
  r.w[2] = __builtin_amdgcn_perm(fbits(b.y), fbits(b.x), 0x07060302);
  r.w[3] = __builtin_amdgcn_perm(fbits(b.w), fbits(b.z), 0x07060302);
  return r.v;
}

typedef __attribute__((address_space(3))) void lds_t;
typedef const __attribute__((address_space(1))) void gbl_t;
__device__ __forceinline__ void gload16(const void* g, void* l) {
  __builtin_amdgcn_global_load_lds((gbl_t*)g, (lds_t*)l, 16, 0, 0);
}

// ---------------- router: logits, top-2, softmax, expert lists, x->bf16 ----------------
__global__ __launch_bounds__(256) void router_kernel(
    const float* __restrict__ x, const float* __restrict__ gw,
    unsigned short* __restrict__ xbf,
    int* __restrict__ cnt, int* __restrict__ slots, float* __restrict__ wts)
{
  const int lane = threadIdx.x & 63;
  const int t = (blockIdx.x * blockDim.x + threadIdx.x) >> 6;
  const float* xr = x + (size_t)t * DDIM;
  float acc[NEXP];
#pragma unroll
  for (int e = 0; e < NEXP; ++e) acc[e] = 0.f;
#pragma unroll
  for (int it = 0; it < DDIM / 256; ++it) {
    const int d = (it * 64 + lane) * 4;
    const float4 xv = *(const float4*)(xr + d);
    u16x4 xb; xb[0]=f2bf(xv.x); xb[1]=f2bf(xv.y); xb[2]=f2bf(xv.z); xb[3]=f2bf(xv.w);
    *(u16x4*)(xbf + (size_t)t * DDIM + d) = xb;
#pragma unroll
    for (int e = 0; e < NEXP; ++e) {
      const float4 gv = *(const float4*)(gw + (size_t)e * DDIM + d);
      acc[e] += xv.x*gv.x + xv.y*gv.y + xv.z*gv.z + xv.w*gv.w;
    }
  }
#pragma unroll
  for (int e = 0; e < NEXP; ++e) {
    float v = acc[e];
#pragma unroll
    for (int off = 32; off > 0; off >>= 1) v += __shfl_xor(v, off);
    acc[e] = v;
  }
  if (lane == 0) {
    int i0 = 0; float v0 = acc[0];
#pragma unroll
    for (int e = 1; e < NEXP; ++e) if (acc[e] > v0) { v0 = acc[e]; i0 = e; }
    int i1 = -1; float v1 = -3.4e38f;
#pragma unroll
    for (int e = 0; e < NEXP; ++e) { if (e == i0) continue; if (acc[e] > v1) { v1 = acc[e]; i1 = e; } }
    const float e1 = __expf(v1 - v0);
    const float w0 = 1.f / (1.f + e1);
    const float w1 = e1 / (1.f + e1);
    const int p0 = atomicAdd(&cnt[i0], 1);
    slots[i0 * TTOK + p0] = t * 2;     wts[i0 * TTOK + p0] = w0;
    const int p1 = atomicAdd(&cnt[i1], 1);
    slots[i1 * TTOK + p1] = t * 2 + 1; wts[i1 * TTOK + p1] = w1;
  }
}

// ---------------- plan: 128-row tiles, padded prefix offsets ----------------
__global__ void plan_kernel(const int* __restrict__ cnt,
                            int* __restrict__ tilemap, int* __restrict__ ntiles,
                            int* __restrict__ po)
{
  if (threadIdx.x == 0 && blockIdx.x == 0) {
    int n = 0, off = 0;
#pragma unroll
    for (int e = 0; e < NEXP; ++e) {
      po[e] = off;
      const int nt = (cnt[e] + 127) >> 7;
      for (int m = 0; m < nt; ++m) tilemap[n++] = (e << 8) | m;
      off += nt << 7;
    }
    ntiles[0] = n;   // <= 40
  }
}

// A chunk swizzle: 16B chunk c of row r at chunk c ^ (r & 7)

// ---- gate+up: 128M x 64N(g)+64N(u), A via gload_lds, B streamed to regs ----
__global__ __launch_bounds__(512, 4) void gateup_kernel(
    const unsigned short* __restrict__ xbf,
    const float* __restrict__ wg, const float* __restrict__ wu,
    const int* __restrict__ cnt, const int* __restrict__ slots,
    const int* __restrict__ po,
    const int* __restrict__ tilemap, const int* __restrict__ ntiles,
    unsigned short* __restrict__ h)
{
  // grid 3520 = 40 slots x 88 panels; XCD swizzle q=440, tile fastest
  const int flat = (blockIdx.x & 7) * 440 + (blockIdx.x >> 3);
  const int ti = flat % 40;
  if (ti >= ntiles[0]) return;
  const int em = tilemap[ti];
  const int e = em >> 8;
  const int mt = em & 255;
  const int n0 = (flat / 40) * 64;
  const int count = cnt[e];
  const int m0 = mt * 128;
  const int abase = po[e] + m0;

  __shared__ unsigned short A[2][128][64];   // 32 KB; epilogue overlay: fp32[128][64]
  __shared__ int rtok[128];

  const int tid = threadIdx.x;
  const int lane = tid & 63;
  const int wid = tid >> 6;

  if (tid < 128) {
    const int idx = m0 + tid;
    rtok[tid] = (idx < count) ? (slots[e * TTOK + idx] >> 1) : (slots[e * TTOK + m0] >> 1);
  }
  __syncthreads();

  // A: gathered token rows, pre-swizzled chunk; each wave stages 16 rows (2 gloads)
  const int aswz = ((lane & 7) ^ ((lane >> 3) & 7)) * 8;
  const unsigned short* ap0 = xbf + (size_t)rtok[wid * 16     + (lane >> 3)] * DDIM + aswz;
  const unsigned short* ap1 = xbf + (size_t)rtok[wid * 16 + 8 + (lane >> 3)] * DDIM + aswz;

  // wave roles: wr = M-half, wc = 32-col group, mat = g/u
  const int wr  = wid & 1;
  const int wc  = (wid >> 1) & 1;
  const int mat = wid >> 2;
  const float* wsel = (mat == 0) ? wg : wu;

  // B frag row pointers (per nf): lane l covers row n0 + wc*32 + nf*16 + (l&15)
  const int fr = lane & 15;
  const int kq = (lane >> 4) * 8;   // k sub-offset within 32-slab
  const float* bp0 = wsel + (size_t)e * IDIM * DDIM + (size_t)(n0 + wc * 32 +      fr) * DDIM + kq;
  const float* bp1 = wsel + (size_t)e * IDIM * DDIM + (size_t)(n0 + wc * 32 + 16 + fr) * DDIM + kq;

  const int kc = lane >> 4;
  const int rsw = fr & 7;

  f32x4 acc[4][2] = {};
  float4 Brg[8];   // B(t): [frag(nf,kk)][2x float4]; frag f = kk*2+nf -> Brg[2f],Brg[2f+1]

  // prologue: A(0) -> buf0; B(0) -> regs
  gload16(ap0, &A[0][wid * 16][0]);
  gload16(ap1, &A[0][wid * 16 + 8][0]);
  __builtin_amdgcn_sched_barrier(0);
  Brg[0] = *(const float4*)(bp0);        Brg[1] = *(const float4*)(bp0 + 4);
  Brg[2] = *(const float4*)(bp1);        Brg[3] = *(const float4*)(bp1 + 4);
  Brg[4] = *(const float4*)(bp0 + 32);   Brg[5] = *(const float4*)(bp0 + 36);
  Brg[6] = *(const float4*)(bp1 + 32);   Brg[7] = *(const float4*)(bp1 + 36);
  asm volatile("s_waitcnt vmcnt(8) lgkmcnt(0)\n\ts_barrier" ::: "memory");

#pragma unroll 2
  for (int t = 0; t < 32; ++t) {
    const int cur = t & 1;
    const int kp = ((t + 1 < 32) ? t + 1 : 31) * 64;

    // 1) A(t+1) -> bufA[cur^1] (oldest vmem of this iter)
    gload16(ap0 + kp, &A[cur ^ 1][wid * 16][0]);
    gload16(ap1 + kp, &A[cur ^ 1][wid * 16 + 8][0]);
    __builtin_amdgcn_sched_barrier(0);

    // 2) convert B(t) regs -> bf16 frags (WAR: loads below wait on these reads)
    bf16x8 bfr[4];
#pragma unroll
    for (int f = 0; f < 4; ++f)
      bfr[f] = (bf16x8)cvt8t(Brg[2 * f], Brg[2 * f + 1]);

    // 3) B(t+1) -> regs (stay in flight across the barrier)
    Brg[0] = *(const float4*)(bp0 + kp);        Brg[1] = *(const float4*)(bp0 + kp + 4);
    Brg[2] = *(const float4*)(bp1 + kp);        Brg[3] = *(const float4*)(bp1 + kp + 4);
    Brg[4] = *(const float4*)(bp0 + kp + 32);   Brg[5] = *(const float4*)(bp0 + kp + 36);
    Brg[6] = *(const float4*)(bp1 + kp);        Brg[6] = *(const float4*)(bp1 + kp + 32);
    Brg[7] = *(const float4*)(bp1 + kp + 36);

    // 4) MFMA on A[cur] x bfr
#pragma unroll
    for (int kk = 0; kk < 2; ++kk) {
      const int cs = ((kk * 4 + kc) ^ rsw) * 8;
      bf16x8 a[4];
#pragma unroll
      for (int mf = 0; mf < 4; ++mf)
        a[mf] = *(const bf16x8*)&A[cur][wr * 64 + mf * 16 + fr][cs];
#pragma unroll
      for (int mf = 0; mf < 4; ++mf)
#pragma unroll
        for (int nf = 0; nf < 2; ++nf)
          acc[mf][nf] = __builtin_amdgcn_mfma_f32_16x16x32_bf16(
              a[mf], bfr[kk * 2 + nf], acc[mf][nf], 0, 0, 0);
    }

    // 5) publish: A(t+1) retired (8 newer B loads stay in flight), LDS drained
    asm volatile("s_waitcnt vmcnt(8) lgkmcnt(0)\n\ts_barrier" ::: "memory");
  }

  // epilogue: u-waves export acc via fp32 LDS overlay; g-waves fuse SiLU
  __syncthreads();
  float* uex = (float*)&A[0][0][0];   // [128][64] fp32 = 32 KB
  if (mat == 1) {
#pragma unroll
    for (int mf = 0; mf < 4; ++mf)
#pragma unroll
      for (int nf = 0; nf < 2; ++nf)
#pragma unroll
        for (int j = 0; j < 4; ++j) {
          const int r = wr * 64 + mf * 16 + (lane >> 4) * 4 + j;
          uex[r * 64 + wc * 32 + nf * 16 + fr] = acc[mf][nf][j];
        }
  }
  __syncthreads();
  if (mat == 0) {
#pragma unroll
    for (int mf = 0; mf < 4; ++mf)
#pragma unroll
      for (int nf = 0; nf < 2; ++nf)
#pragma unroll
        for (int j = 0; j < 4; ++j) {
          const int r = wr * 64 + mf * 16 + (lane >> 4) * 4 + j;
          if (m0 + r < count) {
            const int c = wc * 32 + nf * 16 + fr;
            const float g = acc[mf][nf][j];
            const float u = uex[r * 64 + c];
            const float hv = g / (1.f + __expf(-g)) * u;
            h[(size_t)(abase + r) * IDIM + n0 + c] = f2bf(hv);
          }
        }
  }
}

// ---- down: 128M x 64N, K-split x2, A(h) via gload_lds linear, B streamed to regs ----
__global__ __launch_bounds__(512, 4) void down_kernel(
    const unsigned short* __restrict__ hb,
    const float* __restrict__ wd,
    const int* __restrict__ cnt, const int* __restrict__ slots,
    const float* __restrict__ wts, const int* __restrict__ po,
    const int* __restrict__ tilemap, const int* __restrict__ ntiles,
    float* __restrict__ out)
{
  // grid 2560 = 40 slots x 32 panels x 2 ksplit; XCD swizzle q=320
  const int flat = (blockIdx.x & 7) * 320 + (blockIdx.x >> 3);
  const int ti = flat % 40;
  if (ti >= ntiles[0]) return;
  const int em = tilemap[ti];
  const int e = em >> 8;
  const int mt = em & 255;
  const int rest = flat / 40;          // 0..63
  const int n0 = (rest & 31) * 64;
  const int kbase = (rest >> 5) * (IDIM / 2);
  const int count = cnt[e];
  const int m0 = mt * 128;
  const int abase = po[e] + m0;

  __shared__ unsigned short A[2][128][64];   // 32 KB
  __shared__ int rtok[128];
  __shared__ float rw[128];

  const int tid = threadIdx.x;
  const int lane = tid & 63;
  const int wid = tid >> 6;

  if (tid < 128) {
    const int idx = m0 + tid;
    rtok[tid] = (idx < count) ? (slots[e * TTOK + idx] >> 1) : 0;
    rw[tid] = (idx < count) ? wts[e * TTOK + idx] : 0.f;
  }
  __syncthreads();

  const int aswz = ((lane & 7) ^ ((lane >> 3) & 7)) * 8;
  const unsigned short* ap0 = hb + (size_t)(abase + wid * 16     + (lane >> 3)) * IDIM + kbase + aswz;
  const unsigned short* ap1 = hb + (size_t)(abase + wid * 16 + 8 + (lane >> 3)) * IDIM + kbase + aswz;

  // wave roles: wr = M-half, wc = 16-col strip (4 strips -> BN=64)
  const int wr = wid & 1;
  const int wc = wid >> 1;
  const int fr = lane & 15;
  const int kq = (lane >> 4) * 8;
  const float* bp = wd + (size_t)e * DDIM * IDIM + (size_t)(n0 + wc * 16 + fr) * IDIM + kbase + kq;

  const int kc = lane >> 4;
  const int rsw = fr & 7;

  f32x4 acc[4] = {};
  float4 Brg[4];   // B(t): frag kk -> Brg[2kk], Brg[2kk+1]

  // prologue
  gload16(ap0, &A[0][wid * 16][0]);
  gload16(ap1, &A[0][wid * 16 + 8][0]);
  __builtin_amdgcn_sched_barrier(0);
  Brg[0] = *(const float4*)(bp);        Brg[1] = *(const float4*)(bp + 4);
  Brg[2] = *(const float4*)(bp + 32);   Brg[3] = *(const float4*)(bp + 36);
  asm volatile("s_waitcnt vmcnt(4) lgkmcnt(0)\n\ts_barrier" ::: "memory");

#pragma unroll 2
  for (int t = 0; t < 44; ++t) {
    const int cur = t & 1;
    const int kp = ((t + 1 < 44) ? t + 1 : 43) * 64;

    gload16(ap0 + kp, &A[cur ^ 1][wid * 16][0]);
    gload16(ap1 + kp, &A[cur ^ 1][wid * 16 + 8][0]);
    __builtin_amdgcn_sched_barrier(0);

    bf16x8 bfr[2];
    bfr[0] = (bf16x8)cvt8t(Brg[0], Brg[1]);
    bfr[1] = (bf16x8)cvt8t(Brg[2], Brg[3]);

    Brg[0] = *(const float4*)(bp + kp);        Brg[1] = *(const float4*)(bp + kp + 4);
    Brg[2] = *(const float4*)(bp + kp + 32);   Brg[3] = *(const float4*)(bp + kp + 36);

#pragma unroll
    for (int kk = 0; kk < 2; ++kk) {
      const int cs = ((kk * 4 + kc) ^ rsw) * 8;
      bf16x8 a[4];
#pragma unroll
      for (int mf = 0; mf < 4; ++mf)
        a[mf] = *(const bf16x8*)&A[cur][wr * 64 + mf * 16 + fr][cs];
#pragma unroll
      for (int mf = 0; mf < 4; ++mf)
        acc[mf] = __builtin_amdgcn_mfma_f32_16x16x32_bf16(a[mf], bfr[kk], acc[mf], 0, 0, 0);
    }

    asm volatile("s_waitcnt vmcnt(4) lgkmcnt(0)\n\ts_barrier" ::: "memory");
  }

  // epilogue: weighted scatter-add
#pragma unroll
  for (int mf = 0; mf < 4; ++mf)
#pragma unroll
    for (int j = 0; j < 4; ++j) {
      const int r = wr * 64 + mf * 16 + (lane >> 4) * 4 + j;
      if (m0 + r < count) {
        atomicAdd(out + (size_t)rtok[r] * DDIM + n0 + wc * 16 + fr,
                  acc[mf][j] * rw[r]);
      }
    }
}

extern "C" void kernel_launch(void* const* d_in, const int* in_sizes, int n_in,
                              void* d_out, int out_size, void* d_ws, size_t ws_size,
                              hipStream_t stream) {
  const float* x  = (const float*)d_in[0];
  const float* gw = (const float*)d_in[1];
  const float* wg = (const float*)d_in[2];
  const float* wu = (const float*)d_in[3];
  const float* wd = (const float*)d_in[4];
  float* out = (float*)d_out;

  char* ws = (char*)d_ws;
  unsigned short* xbf = (unsigned short*)ws;                 // 8,388,608 B
  unsigned short* h   = (unsigned short*)(ws + 8388608);     // 5120*5632*2 = 57,671,680 B
  int*   slots = (int*)(ws + 66060288);                      // 65,536 B
  float* wts   = (float*)(ws + 66125824);                    // 65,536 B
  int*   cnt   = (int*)(ws + 66191360);                      // 32 B
  int*   tmap  = (int*)(ws + 66191392);                      // 256 B
  int*   ntl   = (int*)(ws + 66191648);                      // 4 B
  int*   po    = (int*)(ws + 66191652);                      // 32 B

  hipMemsetAsync(cnt, 0, NEXP * sizeof(int), stream);
  hipMemsetAsync(d_out, 0, (size_t)TTOK * DDIM * sizeof(float), stream);

  router_kernel<<<TTOK / 4, 256, 0, stream>>>(x, gw, xbf, cnt, slots, wts);
  plan_kernel<<<1, 64, 0, stream>>>(cnt, tmap, ntl, po);
  gateup_kernel<<<3520, 512, 0, stream>>>(xbf, wg, wu, cnt, slots, po, tmap, ntl, h);
  down_kernel<<<2560, 512, 0, stream>>>(h, wd, cnt, slots, wts, po, tmap, ntl, out);
}

// Round 13
// 788.866 us; speedup vs baseline: 1.8466x; 1.8466x over previous
//
#include <hip/hip_runtime.h>
#include <hip/hip_bf16.h>
#include <stdint.h>

#define TTOK 2048
#define DDIM 2048
#define IDIM 5632
#define NEXP 8

typedef __attribute__((ext_vector_type(8))) short bf16x8;
typedef __attribute__((ext_vector_type(4))) float f32x4;
typedef __attribute__((ext_vector_type(8))) unsigned short u16x8;
typedef __attribute__((ext_vector_type(4))) unsigned short u16x4;

__device__ __forceinline__ unsigned short f2bf(float f) {
  union { float f; uint32_t u; } v; v.f = f;
  uint32_t u = v.u + 0x7fffu + ((v.u >> 16) & 1u);
  return (unsigned short)(u >> 16);
}

__device__ __forceinline__ uint32_t fbits(float f) {
  union { float f; uint32_t u; } v; v.f = f; return v.u;
}

// truncating packed f32x2 -> bf16x2 via v_perm_b32 (1 inst per 2 values)
__device__ __forceinline__ u16x8 cvt8t(float4 a, float4 b) {
  union { u16x8 v; uint32_t w[4]; } r;
  r.w[0] = __builtin_amdgcn_perm(fbits(a.y), fbits(a.x), 0x07060302);
  r.w[1] = __builtin_amdgcn_perm(fbits(a.w), fbits(a.z), 0x07060302);
  r.w[2] = __builtin_amdgcn_perm(fbits(b.y), fbits(b.x), 0x07060302);
  r.w[3] = __builtin_amdgcn_perm(fbits(b.w), fbits(b.z), 0x07060302);
  return r.v;
}

typedef __attribute__((address_space(3))) void lds_t;
typedef const __attribute__((address_space(1))) void gbl_t;
__device__ __forceinline__ void gload16(const void* g, void* l) {
  __builtin_amdgcn_global_load_lds((gbl_t*)g, (lds_t*)l, 16, 0, 0);
}

// gateup pipeline barrier (r9): retire 2 A-gloads, keep 4 B reg-loads in flight
#define PIPE_BAR() asm volatile("s_waitcnt vmcnt(4) lgkmcnt(0)\n\ts_barrier" ::: "memory")

// ---------------- router: logits, top-2, softmax, expert lists, x->bf16 ----------------
__global__ __launch_bounds__(256) void router_kernel(
    const float* __restrict__ x, const float* __restrict__ gw,
    unsigned short* __restrict__ xbf,
    int* __restrict__ cnt, int* __restrict__ slots, float* __restrict__ wts)
{
  const int lane = threadIdx.x & 63;
  const int t = (blockIdx.x * blockDim.x + threadIdx.x) >> 6;
  const float* xr = x + (size_t)t * DDIM;
  float acc[NEXP];
#pragma unroll
  for (int e = 0; e < NEXP; ++e) acc[e] = 0.f;
#pragma unroll
  for (int it = 0; it < DDIM / 256; ++it) {
    const int d = (it * 64 + lane) * 4;
    const float4 xv = *(const float4*)(xr + d);
    u16x4 xb; xb[0]=f2bf(xv.x); xb[1]=f2bf(xv.y); xb[2]=f2bf(xv.z); xb[3]=f2bf(xv.w);
    *(u16x4*)(xbf + (size_t)t * DDIM + d) = xb;
#pragma unroll
    for (int e = 0; e < NEXP; ++e) {
      const float4 gv = *(const float4*)(gw + (size_t)e * DDIM + d);
      acc[e] += xv.x*gv.x + xv.y*gv.y + xv.z*gv.z + xv.w*gv.w;
    }
  }
#pragma unroll
  for (int e = 0; e < NEXP; ++e) {
    float v = acc[e];
#pragma unroll
    for (int off = 32; off > 0; off >>= 1) v += __shfl_xor(v, off);
    acc[e] = v;
  }
  if (lane == 0) {
    int i0 = 0; float v0 = acc[0];
#pragma unroll
    for (int e = 1; e < NEXP; ++e) if (acc[e] > v0) { v0 = acc[e]; i0 = e; }
    int i1 = -1; float v1 = -3.4e38f;
#pragma unroll
    for (int e = 0; e < NEXP; ++e) { if (e == i0) continue; if (acc[e] > v1) { v1 = acc[e]; i1 = e; } }
    const float e1 = __expf(v1 - v0);
    const float w0 = 1.f / (1.f + e1);
    const float w1 = e1 / (1.f + e1);
    const int p0 = atomicAdd(&cnt[i0], 1);
    slots[i0 * TTOK + p0] = t * 2;     wts[i0 * TTOK + p0] = w0;
    const int p1 = atomicAdd(&cnt[i1], 1);
    slots[i1 * TTOK + p1] = t * 2 + 1; wts[i1 * TTOK + p1] = w1;
  }
}

// ---------------- plan: compact (expert, mt) tile list, BM=128 ----------------
__global__ void plan_kernel(const int* __restrict__ cnt,
                            int* __restrict__ tilemap, int* __restrict__ ntiles)
{
  if (threadIdx.x == 0 && blockIdx.x == 0) {
    int n = 0;
#pragma unroll
    for (int e = 0; e < NEXP; ++e) {
      const int nt = (cnt[e] + 127) >> 7;
      for (int m = 0; m < nt; ++m) tilemap[n++] = (e << 8) | m;
    }
    ntiles[0] = n;   // <= 39
  }
}

// A chunk swizzle: 16B chunk c of row r at chunk c ^ (r & 7)

// ---- gate+up (VERBATIM r9): 128M x 64N, g/u split across waves, 16 waves/CU ----
__global__ __launch_bounds__(512, 4) void gateup_kernel(
    const unsigned short* __restrict__ xbf,
    const float* __restrict__ wg, const float* __restrict__ wu,
    const int* __restrict__ cnt, const int* __restrict__ slots,
    const int* __restrict__ tilemap, const int* __restrict__ ntiles,
    unsigned short* __restrict__ h)
{
  const int flat = (blockIdx.x & 7) * 440 + (blockIdx.x >> 3);
  const int ti = flat % 40;
  if (ti >= ntiles[0]) return;
  const int em = tilemap[ti];
  const int e = em >> 8;
  const int mt = em & 255;
  const int n0 = (flat / 40) * 64;
  const int count = cnt[e];
  const int m0 = mt * 128;

  __shared__ unsigned short A[2][128][64];    // 32 KB; epilogue overlay fp32[128][64]
  __shared__ unsigned short Bg[2][64][64];    // 16 KB
  __shared__ unsigned short Bu[2][64][64];    // 16 KB
  __shared__ int rslot[128];
  __shared__ int rtok[128];

  const int tid = threadIdx.x;
  const int lane = tid & 63;
  const int wid = tid >> 6;

  if (tid < 128) {
    const int idx = m0 + tid;
    const int safe = slots[e * TTOK + m0];
    const int s = (idx < count) ? slots[e * TTOK + idx] : safe;
    rslot[tid] = (idx < count) ? s : -1;
    rtok[tid] = s >> 1;
  }
  __syncthreads();

  const int aswz = ((lane & 7) ^ ((lane >> 3) & 7)) * 8;
  const unsigned short* aptr[2];
#pragma unroll
  for (int j = 0; j < 2; ++j) {
    const int arow = wid * 16 + j * 8 + (lane >> 3);
    aptr[j] = xbf + (size_t)rtok[arow] * DDIM + aswz;
  }

  const int mat = wid >> 2;
  unsigned short (*Bm)[64][64] = (mat == 0) ? Bg : Bu;
  const float* wsel = (mat == 0) ? wg : wu;

  const int tidm = tid & 255;
  const int brow = tidm >> 2;
  const int bcb = (tidm & 3) * 2;
  const int bswz = brow & 7;
  const float* msrc = wsel + (size_t)e * IDIM * DDIM + (size_t)(n0 + brow) * DDIM + bcb * 8;

  const int wr = wid & 1;
  const int wc = (wid >> 1) & 1;
  const int fr = lane & 15;
  const int kc = lane >> 4;
  const int rsw = fr & 7;

  f32x4 acc[4][2] = {};

  float4 P[4];
#pragma unroll
  for (int j = 0; j < 2; ++j) gload16(aptr[j], &A[0][wid * 16][0] + j * 512);
#pragma unroll
  for (int q = 0; q < 4; ++q) P[q] = *(const float4*)(msrc + q * 4);
#pragma unroll
  for (int qq = 0; qq < 2; ++qq)
    *(u16x8*)&Bm[0][brow][((bcb + qq) ^ bswz) * 8] = cvt8t(P[qq * 2], P[qq * 2 + 1]);
#pragma unroll
  for (int q = 0; q < 4; ++q) P[q] = *(const float4*)(msrc + 64 + q * 4);
  PIPE_BAR();

#pragma unroll 2
  for (int t = 0; t < 32; ++t) {
    const int cur = t & 1;
    const int kp  = (t + 1 <= 31) ? (t + 1) * 64 : 31 * 64;
    const int kp2 = (t + 2 <= 31) ? (t + 2) * 64 : 31 * 64;

#pragma unroll
    for (int j = 0; j < 2; ++j) gload16(aptr[j] + kp, &A[cur ^ 1][wid * 16][0] + j * 512);
    __builtin_amdgcn_sched_barrier(0);
#pragma unroll
    for (int qq = 0; qq < 2; ++qq)
      *(u16x8*)&Bm[cur ^ 1][brow][((bcb + qq) ^ bswz) * 8] = cvt8t(P[qq * 2], P[qq * 2 + 1]);
#pragma unroll
    for (int q = 0; q < 4; ++q) P[q] = *(const float4*)(msrc + kp2 + q * 4);
    __builtin_amdgcn_sched_barrier(0);

    __builtin_amdgcn_s_setprio(1);
#pragma unroll
    for (int kk = 0; kk < 2; ++kk) {
      bf16x8 a[4], b[2];
      const int cs = ((kk * 4 + kc) ^ rsw) * 8;
#pragma unroll
      for (int mf = 0; mf < 4; ++mf)
        a[mf] = *(const bf16x8*)&A[cur][wr * 64 + mf * 16 + fr][cs];
#pragma unroll
      for (int nf = 0; nf < 2; ++nf)
        b[nf] = *(const bf16x8*)&Bm[cur][wc * 32 + nf * 16 + fr][cs];
#pragma unroll
      for (int mf = 0; mf < 4; ++mf)
#pragma unroll
        for (int nf = 0; nf < 2; ++nf)
          acc[mf][nf] = __builtin_amdgcn_mfma_f32_16x16x32_bf16(a[mf], b[nf], acc[mf][nf], 0, 0, 0);
    }
    __builtin_amdgcn_s_setprio(0);

    PIPE_BAR();
  }

  __syncthreads();
  float* uex = (float*)&A[0][0][0];
  if (mat == 1) {
#pragma unroll
    for (int mf = 0; mf < 4; ++mf)
#pragma unroll
      for (int nf = 0; nf < 2; ++nf)
#pragma unroll
        for (int j = 0; j < 4; ++j) {
          const int r = wr * 64 + mf * 16 + (lane >> 4) * 4 + j;
          uex[r * 64 + wc * 32 + nf * 16 + fr] = acc[mf][nf][j];
        }
  }
  __syncthreads();
  if (mat == 0) {
#pragma unroll
    for (int mf = 0; mf < 4; ++mf)
#pragma unroll
      for (int nf = 0; nf < 2; ++nf)
#pragma unroll
        for (int j = 0; j < 4; ++j) {
          const int r = wr * 64 + mf * 16 + (lane >> 4) * 4 + j;
          const int s = rslot[r];
          if (s >= 0) {
            const int c = wc * 32 + nf * 16 + fr;
            const float g = acc[mf][nf][j];
            const float u = uex[r * 64 + c];
            const float hv = g / (1.f + __expf(-g)) * u;
            h[(size_t)s * IDIM + n0 + c] = f2bf(hv);
          }
        }
  }
}

// ---- down (NEW): 128M x 64N, K-split x2, A AND B via gload_lds (B fp32, frag-time cvt) ----
__global__ __launch_bounds__(256, 4) void down_kernel(
    const unsigned short* __restrict__ h,
    const float* __restrict__ wd,
    const int* __restrict__ cnt, const int* __restrict__ slots,
    const float* __restrict__ wts,
    const int* __restrict__ tilemap, const int* __restrict__ ntiles,
    float* __restrict__ out)
{
  // grid 2560 = 40 slots x 32 panels x 2 ksplit; XCD swizzle q=320
  const int flat = (blockIdx.x & 7) * 320 + (blockIdx.x >> 3);
  const int ti = flat % 40;
  if (ti >= ntiles[0]) return;
  const int em = tilemap[ti];
  const int e = em >> 8;
  const int mt = em & 255;
  const int rest = flat / 40;          // 0..63
  const int n0 = (rest & 31) * 64;
  const int kbase = (rest >> 5) * (IDIM / 2);
  const int count = cnt[e];
  const int m0 = mt * 128;

  __shared__ unsigned short A[2][128][64];   // 32 KB bf16
  __shared__ float Bf[2][64][64];            // 32 KB fp32
  __shared__ int rslot[128];
  __shared__ float rw[128];

  const int tid = threadIdx.x;
  const int lane = tid & 63;
  const int wid = tid >> 6;

  if (tid < 128) {
    const int idx = m0 + tid;
    const int safe = slots[e * TTOK + m0];
    const int s = (idx < count) ? slots[e * TTOK + idx] : safe;
    rslot[tid] = (idx < count) ? s : (safe | 0x40000000);
    rw[tid] = (idx < count) ? wts[e * TTOK + idx] : 0.f;
  }
  __syncthreads();

  // A: gathered h rows (slot order), source chunk pre-swizzled (c ^ (r&7))
  const int aswz = ((lane & 7) ^ ((lane >> 3) & 7)) * 8;
  const unsigned short* aptr[4];
#pragma unroll
  for (int j = 0; j < 4; ++j) {
    const int arow = wid * 32 + j * 8 + (lane >> 3);
    aptr[j] = h + (size_t)(rslot[arow] & 0x3fffffff) * IDIM + kbase + aswz;
  }

  // B: wd rows via gload_lds fp32; 16 chunks/row, source chunk = c ^ (row & 15)
  const float* bptr[4];
#pragma unroll
  for (int g = 0; g < 4; ++g) {
    const int brow = wid * 16 + g * 4 + (lane >> 4);
    const int bch = (lane & 15) ^ (brow & 15);
    bptr[g] = wd + (size_t)e * DDIM * IDIM + (size_t)(n0 + brow) * IDIM + kbase + bch * 4;
  }

  const int wr = wid >> 1, wc = wid & 1;
  const int fr = lane & 15;
  const int kc = lane >> 4;
  const int rsw = fr & 7;

  f32x4 acc[4][2] = {};

  // prologue: stage tile 0 (A 4 + B 4 gloads), publish
#pragma unroll
  for (int j = 0; j < 4; ++j) gload16(aptr[j], &A[0][wid * 32][0] + j * 512);
#pragma unroll
  for (int g = 0; g < 4; ++g) gload16(bptr[g], &Bf[0][wid * 16 + g * 4][0]);
  __syncthreads();

#pragma unroll 2
  for (int t = 0; t < 44; ++t) {
    const int cur = t & 1;
    if (t < 43) {
      const int kp = (t + 1) * 64;
#pragma unroll
      for (int j = 0; j < 4; ++j) gload16(aptr[j] + kp, &A[cur ^ 1][wid * 32][0] + j * 512);
#pragma unroll
      for (int g = 0; g < 4; ++g) gload16(bptr[g] + kp, &Bf[cur ^ 1][wid * 16 + g * 4][0]);
    }
    __builtin_amdgcn_sched_barrier(0);

    __builtin_amdgcn_s_setprio(1);
#pragma unroll
    for (int kk = 0; kk < 2; ++kk) {
      const int cs = ((kk * 4 + kc) ^ rsw) * 8;
      bf16x8 a[4];
#pragma unroll
      for (int mf = 0; mf < 4; ++mf)
        a[mf] = *(const bf16x8*)&A[cur][wr * 64 + mf * 16 + fr][cs];
#pragma unroll
      for (int nf = 0; nf < 2; ++nf) {
        const int br = wc * 32 + nf * 16 + fr;
        const int c0 = kk * 8 + kc * 2;          // logical 16B chunk (4 fp32)
        const float4 fa = *(const float4*)&Bf[cur][br][(c0 ^ fr) * 4];
        const float4 fb = *(const float4*)&Bf[cur][br][((c0 + 1) ^ fr) * 4];
        const bf16x8 b = (bf16x8)cvt8t(fa, fb);
#pragma unroll
        for (int mf = 0; mf < 4; ++mf)
          acc[mf][nf] = __builtin_amdgcn_mfma_f32_16x16x32_bf16(a[mf], b, acc[mf][nf], 0, 0, 0);
      }
    }
    __builtin_amdgcn_s_setprio(0);

    __syncthreads();   // drains this iter's gloads (hidden under MFMA) + publishes buf[cur^1]
  }

  // epilogue: weighted scatter-add
#pragma unroll
  for (int mf = 0; mf < 4; ++mf)
#pragma unroll
    for (int j = 0; j < 4; ++j) {
      const int r = wr * 64 + mf * 16 + (lane >> 4) * 4 + j;
      const int s = rslot[r];
      if (!(s & 0x40000000)) {
        const int t2 = s >> 1;
        const float w = rw[r];
#pragma unroll
        for (int nf = 0; nf < 2; ++nf)
          atomicAdd(out + (size_t)t2 * DDIM + n0 + wc * 32 + nf * 16 + fr,
                    acc[mf][nf][j] * w);
      }
    }
}

extern "C" void kernel_launch(void* const* d_in, const int* in_sizes, int n_in,
                              void* d_out, int out_size, void* d_ws, size_t ws_size,
                              hipStream_t stream) {
  const float* x  = (const float*)d_in[0];
  const float* gw = (const float*)d_in[1];
  const float* wg = (const float*)d_in[2];
  const float* wu = (const float*)d_in[3];
  const float* wd = (const float*)d_in[4];
  float* out = (float*)d_out;

  char* ws = (char*)d_ws;
  unsigned short* xbf = (unsigned short*)ws;                       // 8,388,608 B
  unsigned short* h   = (unsigned short*)(ws + 8388608);           // 46,137,344 B
  int*   slots = (int*)(ws + 8388608 + 46137344);                  // 65,536 B
  float* wts   = (float*)(ws + 8388608 + 46137344 + 65536);        // 65,536 B
  int*   cnt   = (int*)(ws + 8388608 + 46137344 + 131072);         // 32 B
  int*   tmap  = (int*)(ws + 8388608 + 46137344 + 131072 + 32);    // 256 B
  int*   ntl   = (int*)(ws + 8388608 + 46137344 + 131072 + 288);   // 4 B

  hipMemsetAsync(cnt, 0, NEXP * sizeof(int), stream);
  hipMemsetAsync(d_out, 0, (size_t)TTOK * DDIM * sizeof(float), stream);

  router_kernel<<<TTOK / 4, 256, 0, stream>>>(x, gw, xbf, cnt, slots, wts);
  plan_kernel<<<1, 64, 0, stream>>>(cnt, tmap, ntl);
  gateup_kernel<<<3520, 512, 0, stream>>>(xbf, wg, wu, cnt, slots, tmap, ntl, h);
  down_kernel<<<2560, 256, 0, stream>>>(h, wd, cnt, slots, wts, tmap, ntl, out);
}